// Round 5
// baseline (467.390 us; speedup 1.0000x reference)
//
#include <hip/hip_runtime.h>

// ---------------------------------------------------------------------------
// RW_layer: random-walk graph kernel layer, fully factorized.
//   t_step[b,o] = (Σ_s w_step[b,s] x0[b,s,:]) · Zs_step[:,o]
//   x0 = sigmoid(F @ W_in + b_in)
//   w_0 = 1, w_1 = rowsum(adj), w_2 = rowsum(adj) @ adj      (adj symmetric)
// then BN(batch stats) + sigmoid.
// R3: PASSED (absmax 3.9e-3) — inputs are fp32 (probe flag=1).
// R4: 3 launches, fences not barriers. 427us total; k2 ~90-100us inferred
//     (~3.2 TB/s, latency-bound at 8 waves/CU). Timed window also carries
//     ~316us of harness 1-GiB poison fills (uncontrollable floor).
// R6: grid-barrier fusion REGRESSED (k2=196us) — barrier+agent-spin tail.
// R7: launch_bounds(256,8) => 64-VGPR cap => spill catastrophe (k2=314us).
// R8: launch_bounds(256,4) => 128 cap vs ~165 demand => squeeze/spill
//     neutralized the occupancy gain (total unchanged 430us).
// R9 (this round): spill-free max-TLP test. One wave = one batch element,
//   grid 8192x256, NO loop (straight-line body, all loads issue up front),
//   Zfrag direct from L2-hot ZcnS in two 6-frag groups (halves liveness),
//   launch_bounds(256,3) => cap ~170 >= demand ~150-165 => no spill,
//   3 blocks/CU = 12 waves/CU. dstats 64-way replicated (8192 blocks of
//   fp64 atomics); k4 sums 64 replicas.
// ---------------------------------------------------------------------------

typedef short  vec8s  __attribute__((ext_vector_type(8)));
typedef short  vec4s  __attribute__((ext_vector_type(4)));
typedef float  f32x4  __attribute__((ext_vector_type(4)));
typedef unsigned short vec4us __attribute__((ext_vector_type(4)));

#define NB      32768      // batch
#define SS      16         // subgraph size
#define DIN     128
#define HH      64
#define OO      32
#define MM      16
#define NBLK    8192       // k2 grid: one wave per batch element, no loop
#define NREP    64         // dstats replicas

__device__ __forceinline__ float bf2f(unsigned short u) {
    return __uint_as_float(((unsigned int)u) << 16);
}
__device__ __forceinline__ unsigned short f2bf(float f) {   // RNE
    unsigned int u = __float_as_uint(f);
    unsigned int r = (u + 0x7fffu + ((u >> 16) & 1u)) >> 16;
    return (unsigned short)r;
}
template<bool F32>
__device__ __forceinline__ float ldv(const void* p, int i) {
    if (F32) return ((const float*)p)[i];
    return bf2f(((const unsigned short*)p)[i]);
}
// pack 8 fp32 -> 8 bf16 (round-half-up), order-preserving
__device__ __forceinline__ vec8s pack8(f32x4 lo, f32x4 hi) {
    union { unsigned int u[4]; vec8s v; } r;
    unsigned int a0 = __float_as_uint(lo[0]) + 0x8000u;
    unsigned int a1 = __float_as_uint(lo[1]) + 0x8000u;
    unsigned int a2 = __float_as_uint(lo[2]) + 0x8000u;
    unsigned int a3 = __float_as_uint(lo[3]) + 0x8000u;
    unsigned int b0 = __float_as_uint(hi[0]) + 0x8000u;
    unsigned int b1 = __float_as_uint(hi[1]) + 0x8000u;
    unsigned int b2 = __float_as_uint(hi[2]) + 0x8000u;
    unsigned int b3 = __float_as_uint(hi[3]) + 0x8000u;
    r.u[0] = (a0 >> 16) | (a1 & 0xFFFF0000u);
    r.u[1] = (a2 >> 16) | (a3 & 0xFFFF0000u);
    r.u[2] = (b0 >> 16) | (b1 & 0xFFFF0000u);
    r.u[3] = (b2 >> 16) | (b3 & 0xFFFF0000u);
    return r.v;
}

// A[i][j][o] of the symmetric hidden adjacency (relu of triu-packed params)
template<bool F32>
__device__ __forceinline__ float Aval(const void* ahS, int i, int j, int o) {
    if (i == j) return 0.f;
    int a = i < j ? i : j;
    int b = i < j ? j : i;
    int idx = a * 15 - ((a * (a - 1)) >> 1) + (b - a - 1);
    float v = ldv<F32>(ahS, idx * OO + o);
    return v > 0.f ? v : 0.f;
}

// --------------------------- K1: prep + dtype probe ------------------------
template<bool F32>
__device__ void k1_body(const void* fhP, const void* ahP, const void* WP,
                        short* ZcnS, short* WtS, float* cA, float* c2) {
    const int tid = threadIdx.x;
    for (int i = tid; i < MM * OO; i += 256) {
        int p = i >> 5, o = i & 31;
        float s = 0.f;
        for (int m = 0; m < MM; ++m) s += Aval<F32>(ahP, m, p, o);
        cA[i] = s;                      // cA[p,o] = Σ_m A[m,p,o]
    }
    __syncthreads();
    for (int i = tid; i < MM * OO; i += 256) {
        int qq = i >> 5, o = i & 31;
        float s = 0.f;
        for (int p = 0; p < MM; ++p) s += cA[p * OO + o] * Aval<F32>(ahP, p, qq, o);
        c2[i] = s;                      // c2[q,o] = Σ_p cA[p,o] A[p,q,o]
    }
    __syncthreads();
    for (int i = blockIdx.x * 256 + tid; i < 3 * OO * HH; i += 16 * 256) {
        int n = i >> 6, h = i & 63;
        int step = n >> 5, o = n & 31;
        float v = 0.f;
        for (int p = 0; p < MM; ++p) {
            float z = ldv<F32>(fhP, p * (HH * OO) + h * OO + o);
            float w = (step == 0) ? 1.f : (step == 1 ? cA[p * OO + o] : c2[p * OO + o]);
            v += w * z;
        }
        ZcnS[n * HH + h] = (short)f2bf(v);
    }
    for (int i = blockIdx.x * 256 + tid; i < DIN * HH; i += 16 * 256) {
        int h = i >> 7, k = i & 127;
        WtS[h * DIN + k] = (short)f2bf(ldv<F32>(WP, k * HH + h));  // W_in^T
    }
}

__global__ void k1_prep(const void* fhP, const void* ahP, const void* WP,
                        short* ZcnS, short* WtS, double* dstats,
                        const void* featP, int* flag) {
    __shared__ float cA[MM * OO];
    __shared__ float c2[MM * OO];
    __shared__ int chuge, czero, sflag;
    const int tid = threadIdx.x;
    if (tid == 0) { chuge = 0; czero = 0; }
    if (blockIdx.x == 0)
        for (int i = tid; i < NREP * 64; i += 256) dstats[i] = 0.0;  // 64 replicas
    __syncthreads();
    if (tid < 64) {
        const unsigned short* p = (const unsigned short*)featP;
        int h = 0, z = 0;
        for (int i = tid; i < 4096; i += 64) {
            unsigned short u = p[i];
            unsigned e = (u >> 7) & 0xFFu;
            if (e >= 0x90u) h++;             // |v| >= 2^17: impossible for N(0,1)
            if ((u & 0x7FFFu) == 0) z++;     // exact zero
        }
        atomicAdd(&chuge, h);
        atomicAdd(&czero, z);
    }
    __syncthreads();
    if (tid == 0) {
        sflag = (chuge > 8 || czero > 512) ? 1 : 0;
        if (blockIdx.x == 0) *flag = sflag;  // for k2/k4
    }
    __syncthreads();
    if (sflag) k1_body<true>(fhP, ahP, WP, ZcnS, WtS, cA, c2);
    else       k1_body<false>(fhP, ahP, WP, ZcnS, WtS, cA, c2);
}

// --------------------------- K2: main kernel -------------------------------
// ONE WAVE = ONE BATCH ELEMENT. 8192 blocks * 4 waves = 32768 waves = NB.
// Straight-line body: all global loads are independent (no loop-carried
// deps), so they issue up front and overlap. Zcn/W frags come from L2-hot
// prep buffers (28KB shared by all waves). x0buf is WAVE-PRIVATE: only a
// __threadfence_block between its stores and reads (no vmcnt drain).
// MFMA 16x16x32 bf16:
//   A-frag: A[m=lane&15][k=(lane>>4)*8+j], B-frag: B[k=(lane>>4)*8+j][n=lane&15]
//   C/D:    C[row=(lane>>4)*4+reg][col=lane&15]   (m89-verified)
template<bool F32>
__device__ void k2_body(const void* adjP, const void* featP, const void* binP,
                        const short* ZcnS, const short* WtS, float* accOut,
                        double* dsRep, short* myx0, float* bsum, float* bsqs) {
    const int tid  = threadIdx.x;
    const int lane = tid & 63;
    const int hl   = lane & 15;
    const int q    = lane >> 4;
    const int b    = blockIdx.x * 4 + (tid >> 6);   // this wave's batch element

    // ---- HBM loads first: adj row chunk + features A-frags ----
    float a0, a1, a2, a3;
    vec8s af[4];
    if (F32) {
        f32x4 av = *(const f32x4*)((const float*)adjP + b * (SS * SS) + lane * 4);
        a0 = av[0]; a1 = av[1]; a2 = av[2]; a3 = av[3];
        const float* fb = (const float*)featP + b * (SS * DIN) + hl * DIN + q * 8;
        #pragma unroll
        for (int kt = 0; kt < 4; ++kt) {
            f32x4 lo = *(const f32x4*)(fb + kt * 32);
            f32x4 hi = *(const f32x4*)(fb + kt * 32 + 4);
            af[kt] = pack8(lo, hi);
        }
    } else {
        vec4s av = *(const vec4s*)((const short*)adjP + b * (SS * SS) + lane * 4);
        a0 = bf2f((unsigned short)av.x); a1 = bf2f((unsigned short)av.y);
        a2 = bf2f((unsigned short)av.z); a3 = bf2f((unsigned short)av.w);
        const short* fb = (const short*)featP + b * (SS * DIN) + hl * DIN + q * 8;
        #pragma unroll
        for (int kt = 0; kt < 4; ++kt) af[kt] = *(const vec8s*)(fb + kt * 32);
    }

    // ---- L2-hot setup loads (overlap with HBM latency above) ----
    vec8s Wfrag[4][4];
    #pragma unroll
    for (int kt = 0; kt < 4; ++kt)
        #pragma unroll
        for (int nt = 0; nt < 4; ++nt)
            Wfrag[kt][nt] = *(const vec8s*)(WtS + (nt * 16 + hl) * DIN + kt * 32 + q * 8);
    float biasv[4];
    #pragma unroll
    for (int nt = 0; nt < 4; ++nt) biasv[nt] = ldv<F32>(binP, nt * 16 + hl);

    // ---- r = rowsum(adj), w2 = r @ adj (adj symmetric) ----
    // lane holds adj[i][4c+t], i=lane>>2, c=lane&3
    float rsum = a0 + a1 + a2 + a3;
    rsum += __shfl_xor(rsum, 1);
    rsum += __shfl_xor(rsum, 2);            // r[i] at lanes 4i..4i+3
    int cg = lane & 3;
    float rr0 = __shfl(rsum, cg * 16 + 0);  // r[4c+t] lives at lane (4c+t)*4
    float rr1 = __shfl(rsum, cg * 16 + 4);
    float rr2 = __shfl(rsum, cg * 16 + 8);
    float rr3 = __shfl(rsum, cg * 16 + 12);
    float p = a0 * rr0 + a1 * rr1 + a2 * rr2 + a3 * rr3;
    p += __shfl_xor(p, 1);
    p += __shfl_xor(p, 2);                  // w2[i]
    float w1q[4], w2q[4];                   // weights for s = q*4+reg (C rows)
    #pragma unroll
    for (int reg = 0; reg < 4; ++reg) {
        int src = q * 16 + reg * 4;
        w1q[reg] = __shfl(rsum, src);
        w2q[reg] = __shfl(p, src);
    }

    const f32x4 z4 = {0.f, 0.f, 0.f, 0.f};

    // ---- GEMM1: x0pre = F @ W_in   (16x128 @ 128x64, 16 MFMAs) ----
    f32x4 c1[4] = {z4, z4, z4, z4};
    #pragma unroll
    for (int nt = 0; nt < 4; ++nt)
        #pragma unroll
        for (int kt = 0; kt < 4; ++kt)
            c1[nt] = __builtin_amdgcn_mfma_f32_16x16x32_bf16(af[kt], Wfrag[kt][nt], c1[nt], 0, 0, 0);

    // ---- kt=0 Z-frags from L2 (issue early; hide under sigmoid) ----
    vec8s zf0[6];
    #pragma unroll
    for (int t = 0; t < 6; ++t)
        zf0[t] = *(const vec8s*)(ZcnS + (t * 16 + hl) * HH + q * 8);

    // ---- sigmoid -> bf16, transpose C-layout -> (s,h) rows in LDS ----
    #pragma unroll
    for (int nt = 0; nt < 4; ++nt)
        #pragma unroll
        for (int reg = 0; reg < 4; ++reg) {
            float x = c1[nt][reg] + biasv[nt];
            float sg = 1.f / (1.f + __expf(-x));
            unsigned int u = __float_as_uint(sg) + 0x8000u;   // half-up
            myx0[(q * 4 + reg) * 72 + nt * 16 + hl] = (short)(u >> 16);
        }
    __threadfence_block();   // order stores -> frag reads (wave-private LDS)

    // ---- GEMM2: P = x0 @ Zcn^T   (16x64 @ 64x96, 12 MFMAs) ----
    vec8s a2lo = *(const vec8s*)(myx0 + hl * 72 + q * 8);
    vec8s a2hi = *(const vec8s*)(myx0 + hl * 72 + 32 + q * 8);
    vec8s zf1[6];            // kt=1 frags: latency hides under zf0 MFMAs
    #pragma unroll
    for (int t = 0; t < 6; ++t)
        zf1[t] = *(const vec8s*)(ZcnS + (t * 16 + hl) * HH + 32 + q * 8);
    f32x4 cp[6] = {z4, z4, z4, z4, z4, z4};
    #pragma unroll
    for (int t = 0; t < 6; ++t)
        cp[t] = __builtin_amdgcn_mfma_f32_16x16x32_bf16(a2lo, zf0[t], cp[t], 0, 0, 0);
    #pragma unroll
    for (int t = 0; t < 6; ++t)
        cp[t] = __builtin_amdgcn_mfma_f32_16x16x32_bf16(a2hi, zf1[t], cp[t], 0, 0, 0);

    // ---- weighted s-reduction per tile t; n' = t*16+hl, step = t>>1 ----
    float parts[6];
    #pragma unroll
    for (int t = 0; t < 6; ++t) {
        int step = t >> 1;
        float v;
        if (step == 0)      v = cp[t][0] + cp[t][1] + cp[t][2] + cp[t][3];
        else if (step == 1) v = cp[t][0]*w1q[0] + cp[t][1]*w1q[1] + cp[t][2]*w1q[2] + cp[t][3]*w1q[3];
        else                v = cp[t][0]*w2q[0] + cp[t][1]*w2q[1] + cp[t][2]*w2q[2] + cp[t][3]*w2q[3];
        v += __shfl_xor(v, 16);
        v += __shfl_xor(v, 32);
        parts[t] = v;
    }
    float accA = parts[0] + parts[2] + parts[4];   // o = hl
    float accB = parts[1] + parts[3] + parts[5];   // o = 16 + hl
    float accv = ((lane >> 4) & 1) ? accB : accA;  // o = lane & 31 (dup x2)
    accv *= (1.f / 3.f);
    accv = __builtin_isnan(accv) ? 0.f : accv;     // diagnostic net
    if (lane < OO) accOut[b * OO + lane] = accv;

    // ---- BN batch statistics: wave -> block(LDS) -> global(fp64 atomics,
    //      64-way replicated against same-address contention) ----
    if (lane < OO) {
        atomicAdd(&bsum[lane], accv);
        atomicAdd(&bsqs[lane], accv * accv);
    }
    __syncthreads();
    if (tid < OO) {
        atomicAdd(&dsRep[tid],      (double)bsum[tid]);
        atomicAdd(&dsRep[OO + tid], (double)bsqs[tid]);
    }
}

__global__ __launch_bounds__(256, 3) void k2_main(
    const void* adjP, const void* featP, const void* binP,
    const short* ZcnS, const short* WtS, float* accOut,
    double* dstats, const int* flag) {
    __shared__ __align__(16) short x0buf[4][SS * 72];
    __shared__ float bsum[OO];
    __shared__ float bsqs[OO];
    const int tid = threadIdx.x;
    if (tid < OO) { bsum[tid] = 0.f; bsqs[tid] = 0.f; }
    __syncthreads();
    short* myx0 = x0buf[tid >> 6];
    double* dsRep = dstats + (blockIdx.x & (NREP - 1)) * 64;
    if (*flag) k2_body<true>(adjP, featP, binP, ZcnS, WtS, accOut, dsRep, myx0, bsum, bsqs);
    else       k2_body<false>(adjP, featP, binP, ZcnS, WtS, accOut, dsRep, myx0, bsum, bsqs);
}

// ------------------- K4: BN stats finalize + apply + sigmoid ---------------
// Each block redundantly reduces the 64 dstats replicas (4096 fp64 values).
__global__ __launch_bounds__(256) void k4_out(const float* __restrict__ acc,
                                              const double* __restrict__ dstats,
                                              const void* gammaP, const void* betaP,
                                              void* out, const int* flag) {
    __shared__ float sScale[OO], sShift[OO];
    const int tid = threadIdx.x;
    const int f = *flag;
    if (tid < OO) {
        double s1 = 0.0, s2 = 0.0;
        for (int rdup = 0; rdup < NREP; ++rdup) {
            s1 += dstats[rdup * 64 + tid];
            s2 += dstats[rdup * 64 + OO + tid];
        }
        double mean = s1 * (1.0 / (double)NB);
        double ex2  = s2 * (1.0 / (double)NB);
        double var  = ex2 - mean * mean;
        if (var < 0.0) var = 0.0;
        double inv  = 1.0 / sqrt(var + 1e-5);
        float g  = f ? ldv<true>(gammaP, tid) : ldv<false>(gammaP, tid);
        float be = f ? ldv<true>(betaP, tid)  : ldv<false>(betaP, tid);
        sScale[tid] = g * (float)inv;
        sShift[tid] = be - (float)(mean * inv) * g;
    }
    __syncthreads();
    int i = (blockIdx.x * 256 + tid) * 4;
    int o0 = i & 31;
    f32x4 a = *(const f32x4*)(acc + i);
    float r[4];
    #pragma unroll
    for (int j = 0; j < 4; ++j) {
        float z = a[j] * sScale[o0 + j] + sShift[o0 + j];
        r[j] = 1.f / (1.f + __expf(-z));
    }
    if (f) {
        f32x4 w;
        #pragma unroll
        for (int j = 0; j < 4; ++j) w[j] = r[j];
        *(f32x4*)((float*)out + i) = w;
    } else {
        vec4us w;
        #pragma unroll
        for (int j = 0; j < 4; ++j) w[j] = f2bf(r[j]);
        *(vec4us*)((unsigned short*)out + i) = w;
    }
}

// ---------------------------------------------------------------------------
extern "C" void kernel_launch(void* const* d_in, const int* in_sizes, int n_in,
                              void* d_out, int out_size, void* d_ws, size_t ws_size,
                              hipStream_t stream) {
    const void* adjP   = d_in[0];  // (B,16,16)
    const void* featP  = d_in[1];  // (B,16,128)
    const void* WP     = d_in[2];  // (128,64)
    const void* binP   = d_in[3];  // (64,)
    const void* fhP    = d_in[4];  // (16,64,32)
    const void* ahP    = d_in[5];  // (120,32)
    const void* gammaP = d_in[6];  // (32,)
    const void* betaP  = d_in[7];  // (32,)

    char* ws = (char*)d_ws;
    float*  accOut   = (float*)(ws);                    // 32768*32*4 = 4194304 B
    short*  ZcnS     = (short*)(ws + 4194304);          // 96*64*2   = 12288 B
    short*  WtS      = (short*)(ws + 4206592);          // 64*128*2  = 16384 B
    double* dstats   = (double*)(ws + 4222976);         // 64*64*8   = 32768 B
    int*    flag     = (int*)(ws + 4255744);            // 4 B

    hipLaunchKernelGGL(k1_prep,  dim3(16),   dim3(256), 0, stream,
                       fhP, ahP, WP, ZcnS, WtS, dstats, featP, flag);
    hipLaunchKernelGGL(k2_main,  dim3(NBLK), dim3(256), 0, stream,
                       adjP, featP, binP, ZcnS, WtS, accOut, dstats, flag);
    hipLaunchKernelGGL(k4_out,   dim3(1024), dim3(256), 0, stream,
                       accOut, dstats, gammaP, betaP, d_out, flag);
}

// Round 6
// 430.692 us; speedup vs baseline: 1.0852x; 1.0852x over previous
//
#include <hip/hip_runtime.h>

// ---------------------------------------------------------------------------
// RW_layer: random-walk graph kernel layer, fully factorized.
//   t_step[b,o] = (Σ_s w_step[b,s] x0[b,s,:]) · Zs_step[:,o]
//   x0 = sigmoid(F @ W_in + b_in)
//   w_0 = 1, w_1 = rowsum(adj), w_2 = rowsum(adj) @ adj      (adj symmetric)
// then BN(batch stats) + sigmoid.
// R3: PASSED — inputs are fp32 (probe flag=1).
// R4: 3 launches, fences not barriers. 427us total; k2 ~90-100us (latency-
//     bound at 8 waves/CU, serial load->compute chain per iteration).
// R6: grid-barrier fusion regressed (k2=196us). R7: 64-VGPR cap = spill
//     catastrophe (k2=314us). R8: 128 cap vs ~165 demand = squeeze, no gain.
// R9: straight-line 1-elem/wave: compiler MINIMIZED liveness (VGPR=48),
//     sank all loads to uses, k2=164us. Lesson: in-flight bytes cannot be
//     held in VGPRs — compiler either spills or sinks.
// R10 (this round): hold in-flight bytes in LDS via global_load_lds
//   (zero VGPR cost, can't be sunk). R4 structure + double-buffered feature
//   staging + single-buffered adj staging, all WAVE-PRIVATE (no barriers in
//   the loop => no forced vmcnt(0) drains). Deterministic counted pipeline:
//   per iter exactly 9 gload_lds + 1 store; vmcnt retires in issue order =>
//   s_waitcnt vmcnt(1) at iter end == "stage(t+1) complete, newest store may
//   remain". Stage issued at iter top => overlap ~ full compute body.
//   LDS 77KB/block -> 2 blocks/CU, 8 waves/CU, VGPR free (~200, no cap).
// ---------------------------------------------------------------------------

typedef short  vec8s  __attribute__((ext_vector_type(8)));
typedef short  vec4s  __attribute__((ext_vector_type(4)));
typedef float  f32x4  __attribute__((ext_vector_type(4)));
typedef unsigned short vec4us __attribute__((ext_vector_type(4)));

#define NB      32768      // batch
#define SS      16         // subgraph size
#define DIN     128
#define HH      64
#define OO      32
#define MM      16
#define NBLK    512        // k2 grid: 2 blocks/CU (LDS-bound), all resident
#define NREP    8          // dstats replicas

__device__ __forceinline__ float bf2f(unsigned short u) {
    return __uint_as_float(((unsigned int)u) << 16);
}
__device__ __forceinline__ unsigned short f2bf(float f) {   // RNE
    unsigned int u = __float_as_uint(f);
    unsigned int r = (u + 0x7fffu + ((u >> 16) & 1u)) >> 16;
    return (unsigned short)r;
}
template<bool F32>
__device__ __forceinline__ float ldv(const void* p, int i) {
    if (F32) return ((const float*)p)[i];
    return bf2f(((const unsigned short*)p)[i]);
}
// pack 8 fp32 -> 8 bf16 (round-half-up), order-preserving
__device__ __forceinline__ vec8s pack8(f32x4 lo, f32x4 hi) {
    union { unsigned int u[4]; vec8s v; } r;
    unsigned int a0 = __float_as_uint(lo[0]) + 0x8000u;
    unsigned int a1 = __float_as_uint(lo[1]) + 0x8000u;
    unsigned int a2 = __float_as_uint(lo[2]) + 0x8000u;
    unsigned int a3 = __float_as_uint(lo[3]) + 0x8000u;
    unsigned int b0 = __float_as_uint(hi[0]) + 0x8000u;
    unsigned int b1 = __float_as_uint(hi[1]) + 0x8000u;
    unsigned int b2 = __float_as_uint(hi[2]) + 0x8000u;
    unsigned int b3 = __float_as_uint(hi[3]) + 0x8000u;
    r.u[0] = (a0 >> 16) | (a1 & 0xFFFF0000u);
    r.u[1] = (a2 >> 16) | (a3 & 0xFFFF0000u);
    r.u[2] = (b0 >> 16) | (b1 & 0xFFFF0000u);
    r.u[3] = (b2 >> 16) | (b3 & 0xFFFF0000u);
    return r.v;
}

// async global(16B/lane) -> LDS(wave-uniform base + lane*16)
typedef const __attribute__((address_space(1))) unsigned int* gas1_u32;
typedef __attribute__((address_space(3))) unsigned int* las3_u32;
__device__ __forceinline__ void gld16(const void* g, void* l) {
    __builtin_amdgcn_global_load_lds((gas1_u32)g, (las3_u32)l, 16, 0, 0);
}

// A[i][j][o] of the symmetric hidden adjacency (relu of triu-packed params)
template<bool F32>
__device__ __forceinline__ float Aval(const void* ahS, int i, int j, int o) {
    if (i == j) return 0.f;
    int a = i < j ? i : j;
    int b = i < j ? j : i;
    int idx = a * 15 - ((a * (a - 1)) >> 1) + (b - a - 1);
    float v = ldv<F32>(ahS, idx * OO + o);
    return v > 0.f ? v : 0.f;
}

// --------------------------- K1: prep + dtype probe ------------------------
template<bool F32>
__device__ void k1_body(const void* fhP, const void* ahP, const void* WP,
                        short* ZcnS, short* WtS, float* cA, float* c2) {
    const int tid = threadIdx.x;
    for (int i = tid; i < MM * OO; i += 256) {
        int p = i >> 5, o = i & 31;
        float s = 0.f;
        for (int m = 0; m < MM; ++m) s += Aval<F32>(ahP, m, p, o);
        cA[i] = s;                      // cA[p,o] = Σ_m A[m,p,o]
    }
    __syncthreads();
    for (int i = tid; i < MM * OO; i += 256) {
        int qq = i >> 5, o = i & 31;
        float s = 0.f;
        for (int p = 0; p < MM; ++p) s += cA[p * OO + o] * Aval<F32>(ahP, p, qq, o);
        c2[i] = s;                      // c2[q,o] = Σ_p cA[p,o] A[p,q,o]
    }
    __syncthreads();
    for (int i = blockIdx.x * 256 + tid; i < 3 * OO * HH; i += 16 * 256) {
        int n = i >> 6, h = i & 63;
        int step = n >> 5, o = n & 31;
        float v = 0.f;
        for (int p = 0; p < MM; ++p) {
            float z = ldv<F32>(fhP, p * (HH * OO) + h * OO + o);
            float w = (step == 0) ? 1.f : (step == 1 ? cA[p * OO + o] : c2[p * OO + o]);
            v += w * z;
        }
        ZcnS[n * HH + h] = (short)f2bf(v);
    }
    for (int i = blockIdx.x * 256 + tid; i < DIN * HH; i += 16 * 256) {
        int h = i >> 7, k = i & 127;
        WtS[h * DIN + k] = (short)f2bf(ldv<F32>(WP, k * HH + h));  // W_in^T
    }
}

__global__ void k1_prep(const void* fhP, const void* ahP, const void* WP,
                        short* ZcnS, short* WtS, double* dstats,
                        const void* featP, int* flag) {
    __shared__ float cA[MM * OO];
    __shared__ float c2[MM * OO];
    __shared__ int chuge, czero, sflag;
    const int tid = threadIdx.x;
    if (tid == 0) { chuge = 0; czero = 0; }
    if (blockIdx.x == 0)
        for (int i = tid; i < NREP * 64; i += 256) dstats[i] = 0.0;
    __syncthreads();
    if (tid < 64) {
        const unsigned short* p = (const unsigned short*)featP;
        int h = 0, z = 0;
        for (int i = tid; i < 4096; i += 64) {
            unsigned short u = p[i];
            unsigned e = (u >> 7) & 0xFFu;
            if (e >= 0x90u) h++;             // |v| >= 2^17: impossible for N(0,1)
            if ((u & 0x7FFFu) == 0) z++;     // exact zero
        }
        atomicAdd(&chuge, h);
        atomicAdd(&czero, z);
    }
    __syncthreads();
    if (tid == 0) {
        sflag = (chuge > 8 || czero > 512) ? 1 : 0;
        if (blockIdx.x == 0) *flag = sflag;  // for k2/k4
    }
    __syncthreads();
    if (sflag) k1_body<true>(fhP, ahP, WP, ZcnS, WtS, cA, c2);
    else       k1_body<false>(fhP, ahP, WP, ZcnS, WtS, cA, c2);
}

// --------------------------- K2: main kernel -------------------------------
// One wave per batch element per iteration; 512 blocks * 4 waves = 2048
// waves, 16 iters each. fp32 path: async LDS staging pipeline (see header).
// Per-wave stage layout (floats): [0..2047] fbuf0, [2048..4095] fbuf1,
// [4096..4351] abuf (single-buffered: adj(t) is consumed into regs before
// stage(t+1) is issued — sched_barrier enforces the order).
// MFMA 16x16x32 bf16:
//   A-frag: A[m=lane&15][k=(lane>>4)*8+j], B-frag: B[k=(lane>>4)*8+j][n=lane&15]
//   C/D:    C[row=(lane>>4)*4+reg][col=lane&15]   (m89-verified)
__device__ void k2_body_f32(const float* adjF, const float* featF, const float* binF,
                            const short* ZcnS, const short* WtS, float* accOut,
                            double* dsRep, short* myx0, float* stg,
                            float* bsum, float* bsqs) {
    const int tid  = threadIdx.x;
    const int lane = tid & 63;
    const int hl   = lane & 15;
    const int q    = lane >> 4;

    // persistent B-frags: W (16 vec8s) + Zcn (12 vec8s), loaded once (L2-hot)
    vec8s Wfrag[4][4];
    #pragma unroll
    for (int kt = 0; kt < 4; ++kt)
        #pragma unroll
        for (int nt = 0; nt < 4; ++nt)
            Wfrag[kt][nt] = *(const vec8s*)(WtS + (nt * 16 + hl) * DIN + kt * 32 + q * 8);
    vec8s Zfrag[2][6];
    #pragma unroll
    for (int kt = 0; kt < 2; ++kt)
        #pragma unroll
        for (int t = 0; t < 6; ++t)
            Zfrag[kt][t] = *(const vec8s*)(ZcnS + (t * 16 + hl) * HH + kt * 32 + q * 8);
    float biasv[4];
    #pragma unroll
    for (int nt = 0; nt < 4; ++nt) biasv[nt] = binF[nt * 16 + hl];

    const f32x4 z4 = {0.f, 0.f, 0.f, 0.f};
    float ls = 0.f, lss = 0.f;
    const int wgid = blockIdx.x * 4 + (tid >> 6);
    int b = wgid;

    // ---- prologue: stage tile 0 (9 async loads), drain everything ----
    {
        const float* fB = featF + (size_t)b * 2048;
        #pragma unroll
        for (int i = 0; i < 8; ++i) gld16(fB + i * 256 + lane * 4, stg + i * 256);
        gld16(adjF + (size_t)b * 256 + lane * 4, stg + 4096);
    }
    asm volatile("s_waitcnt vmcnt(0)" ::: "memory");
    __builtin_amdgcn_sched_barrier(0);

    #pragma unroll 1
    for (int it = 0; it < 16; ++it) {
        float* fb = stg + ((it & 1) * 2048);

        // ---- adj(t) from LDS -> regs; consume to force the lgkm wait ----
        f32x4 av = *(const f32x4*)(stg + 4096 + lane * 4);
        float a0 = av[0], a1 = av[1], a2 = av[2], a3 = av[3];
        float rsum = a0 + a1 + a2 + a3;
        __builtin_amdgcn_sched_barrier(0);   // adj consumed BEFORE stage below

        // ---- stage tile t+1 early: 9 async loads, zero VGPR cost ----
        if (it < 15) {
            int bn = b + 2048;
            const float* fN = featF + (size_t)bn * 2048;
            float* fd = stg + (((it + 1) & 1) * 2048);
            #pragma unroll
            for (int i = 0; i < 8; ++i) gld16(fN + i * 256 + lane * 4, fd + i * 256);
            gld16(adjF + (size_t)bn * 256 + lane * 4, stg + 4096);
        }
        __builtin_amdgcn_sched_barrier(0);   // keep stage issue early

        // ---- r = rowsum(adj), w2 = r @ adj (adj symmetric) ----
        // lane holds adj[i][4c+t], i=lane>>2, c=lane&3
        rsum += __shfl_xor(rsum, 1);
        rsum += __shfl_xor(rsum, 2);            // r[i] at lanes 4i..4i+3
        int cg = lane & 3;
        float rr0 = __shfl(rsum, cg * 16 + 0);  // r[4c+t] lives at lane (4c+t)*4
        float rr1 = __shfl(rsum, cg * 16 + 4);
        float rr2 = __shfl(rsum, cg * 16 + 8);
        float rr3 = __shfl(rsum, cg * 16 + 12);
        float p = a0 * rr0 + a1 * rr1 + a2 * rr2 + a3 * rr3;
        p += __shfl_xor(p, 1);
        p += __shfl_xor(p, 2);                  // w2[i]
        float w1q[4], w2q[4];                   // weights for s = q*4+reg (C rows)
        #pragma unroll
        for (int reg = 0; reg < 4; ++reg) {
            int src = q * 16 + reg * 4;
            w1q[reg] = __shfl(rsum, src);
            w2q[reg] = __shfl(p, src);
        }

        // ---- features(t) from LDS: 8x ds_read_b128 + pack -> A-frags ----
        vec8s af[4];
        #pragma unroll
        for (int kt = 0; kt < 4; ++kt) {
            f32x4 lo = *(const f32x4*)(fb + hl * 128 + kt * 32 + q * 8);
            f32x4 hi = *(const f32x4*)(fb + hl * 128 + kt * 32 + q * 8 + 4);
            af[kt] = pack8(lo, hi);
        }

        // ---- GEMM1: x0pre = F @ W_in   (16x128 @ 128x64, 16 MFMAs) ----
        f32x4 c1[4] = {z4, z4, z4, z4};
        #pragma unroll
        for (int nt = 0; nt < 4; ++nt)
            #pragma unroll
            for (int kt = 0; kt < 4; ++kt)
                c1[nt] = __builtin_amdgcn_mfma_f32_16x16x32_bf16(af[kt], Wfrag[kt][nt], c1[nt], 0, 0, 0);

        // ---- sigmoid -> bf16, transpose C-layout -> (s,h) rows in LDS ----
        #pragma unroll
        for (int nt = 0; nt < 4; ++nt)
            #pragma unroll
            for (int reg = 0; reg < 4; ++reg) {
                float x = c1[nt][reg] + biasv[nt];
                float sg = 1.f / (1.f + __expf(-x));
                unsigned int u = __float_as_uint(sg) + 0x8000u;   // half-up
                myx0[(q * 4 + reg) * 72 + nt * 16 + hl] = (short)(u >> 16);
            }
        __threadfence_block();   // order stores -> frag reads (wave-private LDS)

        // ---- GEMM2: P = x0 @ Zcn^T   (16x64 @ 64x96, 12 MFMAs) ----
        vec8s a2lo = *(const vec8s*)(myx0 + hl * 72 + q * 8);
        vec8s a2hi = *(const vec8s*)(myx0 + hl * 72 + 32 + q * 8);
        __threadfence_block();   // order frag reads -> next iter's stores (WAR)
        f32x4 cp[6] = {z4, z4, z4, z4, z4, z4};
        #pragma unroll
        for (int t = 0; t < 6; ++t)
            cp[t] = __builtin_amdgcn_mfma_f32_16x16x32_bf16(a2lo, Zfrag[0][t], cp[t], 0, 0, 0);
        #pragma unroll
        for (int t = 0; t < 6; ++t)
            cp[t] = __builtin_amdgcn_mfma_f32_16x16x32_bf16(a2hi, Zfrag[1][t], cp[t], 0, 0, 0);

        // ---- weighted s-reduction per tile t; n' = t*16+hl, step = t>>1 ----
        float parts[6];
        #pragma unroll
        for (int t = 0; t < 6; ++t) {
            int step = t >> 1;
            float v;
            if (step == 0)      v = cp[t][0] + cp[t][1] + cp[t][2] + cp[t][3];
            else if (step == 1) v = cp[t][0]*w1q[0] + cp[t][1]*w1q[1] + cp[t][2]*w1q[2] + cp[t][3]*w1q[3];
            else                v = cp[t][0]*w2q[0] + cp[t][1]*w2q[1] + cp[t][2]*w2q[2] + cp[t][3]*w2q[3];
            v += __shfl_xor(v, 16);
            v += __shfl_xor(v, 32);
            parts[t] = v;
        }
        float accA = parts[0] + parts[2] + parts[4];   // o = hl
        float accB = parts[1] + parts[3] + parts[5];   // o = 16 + hl
        float accv = ((lane >> 4) & 1) ? accB : accA;  // o = lane & 31 (dup x2)
        accv *= (1.f / 3.f);
        accv = __builtin_isnan(accv) ? 0.f : accv;     // diagnostic net
        if (lane < OO) accOut[b * OO + lane] = accv;   // 1 store (counted)
        ls  += accv;
        lss += accv * accv;

        // ---- counted drain: all but the newest VMEM op (= the store) done
        //      => stage(t+1)'s 9 loads landed; buffers valid next iter ----
        if (it < 15) {
            asm volatile("s_waitcnt vmcnt(1)" ::: "memory");
            __builtin_amdgcn_sched_barrier(0);
        }
        b += 2048;
    }

    // ---- BN batch statistics: wave -> block(LDS) -> global(fp64 atomics) ----
    if (lane < OO) {
        atomicAdd(&bsum[lane], ls);
        atomicAdd(&bsqs[lane], lss);
    }
    __syncthreads();
    if (tid < OO) {
        atomicAdd(&dsRep[tid],      (double)bsum[tid]);
        atomicAdd(&dsRep[OO + tid], (double)bsqs[tid]);
    }
}

// bf16-input fallback path (never exercised on this harness: flag=1 measured
// every round) — R4's proven direct-load body, unchanged.
__device__ void k2_body_bf16(const void* adjP, const void* featP, const void* binP,
                             const short* ZcnS, const short* WtS, float* accOut,
                             double* dsRep, short* myx0, float* bsum, float* bsqs) {
    const int tid  = threadIdx.x;
    const int lane = tid & 63;
    const int hl   = lane & 15;
    const int q    = lane >> 4;

    vec8s Wfrag[4][4];
    #pragma unroll
    for (int kt = 0; kt < 4; ++kt)
        #pragma unroll
        for (int nt = 0; nt < 4; ++nt)
            Wfrag[kt][nt] = *(const vec8s*)(WtS + (nt * 16 + hl) * DIN + kt * 32 + q * 8);
    vec8s Zfrag[2][6];
    #pragma unroll
    for (int kt = 0; kt < 2; ++kt)
        #pragma unroll
        for (int t = 0; t < 6; ++t)
            Zfrag[kt][t] = *(const vec8s*)(ZcnS + (t * 16 + hl) * HH + kt * 32 + q * 8);
    float biasv[4];
    #pragma unroll
    for (int nt = 0; nt < 4; ++nt) biasv[nt] = ldv<false>(binP, nt * 16 + hl);

    const f32x4 z4 = {0.f, 0.f, 0.f, 0.f};
    float ls = 0.f, lss = 0.f;
    const int wgid = blockIdx.x * 4 + (tid >> 6);

    #pragma unroll 1
    for (int b = wgid; b < NB; b += 2048) {
        vec4s av = *(const vec4s*)((const short*)adjP + b * (SS * SS) + lane * 4);
        float a0 = bf2f((unsigned short)av.x), a1 = bf2f((unsigned short)av.y);
        float a2 = bf2f((unsigned short)av.z), a3 = bf2f((unsigned short)av.w);
        const short* fbg = (const short*)featP + b * (SS * DIN) + hl * DIN + q * 8;
        vec8s af[4];
        #pragma unroll
        for (int kt = 0; kt < 4; ++kt) af[kt] = *(const vec8s*)(fbg + kt * 32);

        float rsum = a0 + a1 + a2 + a3;
        rsum += __shfl_xor(rsum, 1);
        rsum += __shfl_xor(rsum, 2);
        int cg = lane & 3;
        float rr0 = __shfl(rsum, cg * 16 + 0);
        float rr1 = __shfl(rsum, cg * 16 + 4);
        float rr2 = __shfl(rsum, cg * 16 + 8);
        float rr3 = __shfl(rsum, cg * 16 + 12);
        float p = a0 * rr0 + a1 * rr1 + a2 * rr2 + a3 * rr3;
        p += __shfl_xor(p, 1);
        p += __shfl_xor(p, 2);
        float w1q[4], w2q[4];
        #pragma unroll
        for (int reg = 0; reg < 4; ++reg) {
            int src = q * 16 + reg * 4;
            w1q[reg] = __shfl(rsum, src);
            w2q[reg] = __shfl(p, src);
        }

        f32x4 c1[4] = {z4, z4, z4, z4};
        #pragma unroll
        for (int nt = 0; nt < 4; ++nt)
            #pragma unroll
            for (int kt = 0; kt < 4; ++kt)
                c1[nt] = __builtin_amdgcn_mfma_f32_16x16x32_bf16(af[kt], Wfrag[kt][nt], c1[nt], 0, 0, 0);

        #pragma unroll
        for (int nt = 0; nt < 4; ++nt)
            #pragma unroll
            for (int reg = 0; reg < 4; ++reg) {
                float x = c1[nt][reg] + biasv[nt];
                float sg = 1.f / (1.f + __expf(-x));
                unsigned int u = __float_as_uint(sg) + 0x8000u;
                myx0[(q * 4 + reg) * 72 + nt * 16 + hl] = (short)(u >> 16);
            }
        __threadfence_block();
        vec8s a2lo = *(const vec8s*)(myx0 + hl * 72 + q * 8);
        vec8s a2hi = *(const vec8s*)(myx0 + hl * 72 + 32 + q * 8);
        __threadfence_block();
        f32x4 cp[6] = {z4, z4, z4, z4, z4, z4};
        #pragma unroll
        for (int t = 0; t < 6; ++t)
            cp[t] = __builtin_amdgcn_mfma_f32_16x16x32_bf16(a2lo, Zfrag[0][t], cp[t], 0, 0, 0);
        #pragma unroll
        for (int t = 0; t < 6; ++t)
            cp[t] = __builtin_amdgcn_mfma_f32_16x16x32_bf16(a2hi, Zfrag[1][t], cp[t], 0, 0, 0);

        float parts[6];
        #pragma unroll
        for (int t = 0; t < 6; ++t) {
            int step = t >> 1;
            float v;
            if (step == 0)      v = cp[t][0] + cp[t][1] + cp[t][2] + cp[t][3];
            else if (step == 1) v = cp[t][0]*w1q[0] + cp[t][1]*w1q[1] + cp[t][2]*w1q[2] + cp[t][3]*w1q[3];
            else                v = cp[t][0]*w2q[0] + cp[t][1]*w2q[1] + cp[t][2]*w2q[2] + cp[t][3]*w2q[3];
            v += __shfl_xor(v, 16);
            v += __shfl_xor(v, 32);
            parts[t] = v;
        }
        float accA = parts[0] + parts[2] + parts[4];
        float accB = parts[1] + parts[3] + parts[5];
        float accv = ((lane >> 4) & 1) ? accB : accA;
        accv *= (1.f / 3.f);
        accv = __builtin_isnan(accv) ? 0.f : accv;
        if (lane < OO) accOut[b * OO + lane] = accv;
        ls  += accv;
        lss += accv * accv;
    }

    if (lane < OO) {
        atomicAdd(&bsum[lane], ls);
        atomicAdd(&bsqs[lane], lss);
    }
    __syncthreads();
    if (tid < OO) {
        atomicAdd(&dsRep[tid],      (double)bsum[tid]);
        atomicAdd(&dsRep[OO + tid], (double)bsqs[tid]);
    }
}

__global__ __launch_bounds__(256, 2) void k2_main(
    const void* adjP, const void* featP, const void* binP,
    const short* ZcnS, const short* WtS, float* accOut,
    double* dstats, const int* flag) {
    // per-wave: fbuf0(2048f) | fbuf1(2048f) | abuf(256f) = 17408B; x0 2304B
    __shared__ __align__(16) float stg[4][4352];
    __shared__ __align__(16) short x0buf[4][SS * 72];
    __shared__ float bsum[OO];
    __shared__ float bsqs[OO];
    const int tid = threadIdx.x;
    if (tid < OO) { bsum[tid] = 0.f; bsqs[tid] = 0.f; }
    __syncthreads();
    short* myx0 = x0buf[tid >> 6];
    float* stgw = stg[tid >> 6];
    double* dsRep = dstats + (blockIdx.x & (NREP - 1)) * 64;
    if (*flag)
        k2_body_f32((const float*)adjP, (const float*)featP, (const float*)binP,
                    ZcnS, WtS, accOut, dsRep, myx0, stgw, bsum, bsqs);
    else
        k2_body_bf16(adjP, featP, binP, ZcnS, WtS, accOut, dsRep, myx0, bsum, bsqs);
}

// ------------------- K4: BN stats finalize + apply + sigmoid ---------------
// Each block redundantly reduces the 8 dstats replicas.
__global__ __launch_bounds__(256) void k4_out(const float* __restrict__ acc,
                                              const double* __restrict__ dstats,
                                              const void* gammaP, const void* betaP,
                                              void* out, const int* flag) {
    __shared__ float sScale[OO], sShift[OO];
    const int tid = threadIdx.x;
    const int f = *flag;
    if (tid < OO) {
        double s1 = 0.0, s2 = 0.0;
        #pragma unroll
        for (int rdup = 0; rdup < NREP; ++rdup) {
            s1 += dstats[rdup * 64 + tid];
            s2 += dstats[rdup * 64 + OO + tid];
        }
        double mean = s1 * (1.0 / (double)NB);
        double ex2  = s2 * (1.0 / (double)NB);
        double var  = ex2 - mean * mean;
        if (var < 0.0) var = 0.0;
        double inv  = 1.0 / sqrt(var + 1e-5);
        float g  = f ? ldv<true>(gammaP, tid) : ldv<false>(gammaP, tid);
        float be = f ? ldv<true>(betaP, tid)  : ldv<false>(betaP, tid);
        sScale[tid] = g * (float)inv;
        sShift[tid] = be - (float)(mean * inv) * g;
    }
    __syncthreads();
    int i = (blockIdx.x * 256 + tid) * 4;
    int o0 = i & 31;
    f32x4 a = *(const f32x4*)(acc + i);
    float r[4];
    #pragma unroll
    for (int j = 0; j < 4; ++j) {
        float z = a[j] * sScale[o0 + j] + sShift[o0 + j];
        r[j] = 1.f / (1.f + __expf(-z));
    }
    if (f) {
        f32x4 w;
        #pragma unroll
        for (int j = 0; j < 4; ++j) w[j] = r[j];
        *(f32x4*)((float*)out + i) = w;
    } else {
        vec4us w;
        #pragma unroll
        for (int j = 0; j < 4; ++j) w[j] = f2bf(r[j]);
        *(vec4us*)((unsigned short*)out + i) = w;
    }
}

// ---------------------------------------------------------------------------
extern "C" void kernel_launch(void* const* d_in, const int* in_sizes, int n_in,
                              void* d_out, int out_size, void* d_ws, size_t ws_size,
                              hipStream_t stream) {
    const void* adjP   = d_in[0];  // (B,16,16)
    const void* featP  = d_in[1];  // (B,16,128)
    const void* WP     = d_in[2];  // (128,64)
    const void* binP   = d_in[3];  // (64,)
    const void* fhP    = d_in[4];  // (16,64,32)
    const void* ahP    = d_in[5];  // (120,32)
    const void* gammaP = d_in[6];  // (32,)
    const void* betaP  = d_in[7];  // (32,)

    char* ws = (char*)d_ws;
    float*  accOut   = (float*)(ws);                    // 32768*32*4 = 4194304 B
    short*  ZcnS     = (short*)(ws + 4194304);          // 96*64*2   = 12288 B
    short*  WtS      = (short*)(ws + 4206592);          // 64*128*2  = 16384 B
    double* dstats   = (double*)(ws + 4222976);         // 8*64*8    = 4096 B
    int*    flag     = (int*)(ws + 4227072);            // 4 B

    hipLaunchKernelGGL(k1_prep,  dim3(16),   dim3(256), 0, stream,
                       fhP, ahP, WP, ZcnS, WtS, dstats, featP, flag);
    hipLaunchKernelGGL(k2_main,  dim3(NBLK), dim3(256), 0, stream,
                       adjP, featP, binP, ZcnS, WtS, accOut, dstats, flag);
    hipLaunchKernelGGL(k4_out,   dim3(1024), dim3(256), 0, stream,
                       accOut, dstats, gammaP, betaP, d_out, flag);
}